// Round 1
// baseline (591.131 us; speedup 1.0000x reference)
//
#include <hip/hip_runtime.h>

typedef __attribute__((ext_vector_type(8))) short bf16x8;
typedef __attribute__((ext_vector_type(4))) float f32x4;
typedef unsigned short u16;
typedef unsigned int u32;

// ---------- constants ----------
#define NWIN 2048
#define P 64
#define C 256
#define MSEL 1536
#define KEEP 48
#define REAL 40
#define H 8
#define DH 32
#define MROWS (MSEL * REAL)          // 61440 rows in the compacted activation matrix

// ws layout (u16 element offsets)
#define OFF_WQKVT  0                  // [768][256]
#define OFF_PROJT  196608             // [256][256]
#define OFF_W1T    262144             // [1024][256]
#define OFF_W2T    524288             // [256][1024]
#define OFF_A      786432             // [61440][256] bf16  (LN2 rows)
#define OFF_QKV    16515072           // [61440][768] bf16
#define OFF_ATTNO  63700992           // [61440][256] bf16
#define OFF_XA     79429632           // [61440][256] bf16
#define OFF_H      16515072           // [61440][1024] bf16, aliases QKV+ATTNO (both dead)

__device__ __forceinline__ u16 f2bf(float f) {
    u32 u = __float_as_uint(f);
    u += 0x7FFF + ((u >> 16) & 1);   // RNE
    return (u16)(u >> 16);
}
__device__ __forceinline__ float bf2f(u16 h) { return __uint_as_float(((u32)h) << 16); }

// ---------- weight prep: fp32 [K][N] -> bf16 [N][K] ----------
__global__ __launch_bounds__(256) void prep_weights(const float* __restrict__ qkv_w,
                                                    const float* __restrict__ proj_w,
                                                    const float* __restrict__ w1,
                                                    const float* __restrict__ w2,
                                                    u16* __restrict__ ws) {
    int i = blockIdx.x * 256 + threadIdx.x;   // 786432 total
    float v; int o;
    if (i < 196608) {                 // WqkvT[n][k] = qkv_w[k*768+n]
        int n = i >> 8, k = i & 255; v = qkv_w[k * 768 + n]; o = OFF_WQKVT + i;
    } else if (i < 262144) {          // ProjT
        int j = i - 196608; int n = j >> 8, k = j & 255; v = proj_w[k * 256 + n]; o = i;
    } else if (i < 524288) {          // W1T [1024][256]
        int j = i - 262144; int n = j >> 8, k = j & 255; v = w1[k * 1024 + n]; o = i;
    } else {                          // W2T [256][1024]
        int j = i - 524288; int n = j >> 10, k = j & 1023; v = w2[k * 256 + n]; o = i;
    }
    ws[o] = f2bf(v);
}

// ---------- LN1 over all (N*P, C) rows -> d_out fp32 ----------
__global__ __launch_bounds__(256) void ln1_kernel(const float* __restrict__ x,
                                                  const float* __restrict__ g,
                                                  const float* __restrict__ b,
                                                  float* __restrict__ out) {
    int row = blockIdx.x * 4 + (threadIdx.x >> 6);
    int l = threadIdx.x & 63;
    const float4 v = *(const float4*)(x + (size_t)row * C + l * 4);
    float s = v.x + v.y + v.z + v.w;
    float q = v.x * v.x + v.y * v.y + v.z * v.z + v.w * v.w;
    #pragma unroll
    for (int m = 1; m < 64; m <<= 1) { s += __shfl_xor(s, m); q += __shfl_xor(q, m); }
    float mu = s * (1.0f / C);
    float var = q * (1.0f / C) - mu * mu;
    float rs = rsqrtf(var + 1e-5f);
    float4 gg = *(const float4*)(g + l * 4);
    float4 bb = *(const float4*)(b + l * 4);
    float4 o;
    o.x = (v.x - mu) * rs * gg.x + bb.x;
    o.y = (v.y - mu) * rs * gg.y + bb.y;
    o.z = (v.z - mu) * rs * gg.z + bb.z;
    o.w = (v.w - mu) * rs * gg.w + bb.w;
    *(float4*)(out + (size_t)row * C + l * 4) = o;
}

// ---------- LN2 on real rows of selected windows -> A bf16 ----------
__global__ __launch_bounds__(256) void ln2_kernel(const float* __restrict__ ln1,
                                                  const float* __restrict__ g,
                                                  const float* __restrict__ b,
                                                  const int* __restrict__ asy,
                                                  const int* __restrict__ iwin,
                                                  u16* __restrict__ A) {
    int r = blockIdx.x * 4 + (threadIdx.x >> 6);
    int l = threadIdx.x & 63;
    int flat = asy[r];
    int m = flat >> 6, p = flat & 63;
    int w = iwin[m];
    const float4 v = *(const float4*)(ln1 + ((size_t)w * P + p) * C + l * 4);
    float s = v.x + v.y + v.z + v.w;
    float q = v.x * v.x + v.y * v.y + v.z * v.z + v.w * v.w;
    #pragma unroll
    for (int mm = 1; mm < 64; mm <<= 1) { s += __shfl_xor(s, mm); q += __shfl_xor(q, mm); }
    float mu = s * (1.0f / C);
    float var = q * (1.0f / C) - mu * mu;
    float rs = rsqrtf(var + 1e-5f);
    float4 gg = *(const float4*)(g + l * 4);
    float4 bb = *(const float4*)(b + l * 4);
    ushort4 o;
    o.x = f2bf((v.x - mu) * rs * gg.x + bb.x);
    o.y = f2bf((v.y - mu) * rs * gg.y + bb.y);
    o.z = f2bf((v.z - mu) * rs * gg.z + bb.z);
    o.w = f2bf((v.w - mu) * rs * gg.w + bb.w);
    *(ushort4*)(A + (size_t)r * C + l * 4) = o;
}

// ---------- generic 128x128-tile bf16 MFMA GEMM: C = A[MxK] * B^T[NxK], epilogue functor ----------
// LDS rows padded to 40 elems (80B) to spread banks.
template <int N, int K, class Epi>
__global__ __launch_bounds__(256) void gemm_bt(const u16* __restrict__ A,
                                               const u16* __restrict__ B, Epi epi) {
    constexpr int NB = N / 128;
    int bid = blockIdx.x;
    int bm = bid / NB, bn = bid % NB;
    __shared__ u16 lA[128 * 40], lB[128 * 40];
    int t = threadIdx.x;
    int l = t & 63, w = t >> 6;
    int wr = w >> 1, wc = w & 1;
    int l15 = l & 15, g4 = l >> 4;

    f32x4 acc[4][4];
    #pragma unroll
    for (int a = 0; a < 4; a++)
        #pragma unroll
        for (int bb = 0; bb < 4; bb++)
            #pragma unroll
            for (int i = 0; i < 4; i++) acc[a][bb][i] = 0.0f;

    int sr = t >> 1, sh = (t & 1) * 16;
    const u16* gA = A + (size_t)(bm * 128 + sr) * K + sh;
    const u16* gB = B + (size_t)(bn * 128 + sr) * K + sh;
    u16* wA = lA + sr * 40 + sh;
    u16* wB = lB + sr * 40 + sh;

    for (int k0 = 0; k0 < K; k0 += 32) {
        uint4 a0 = *(const uint4*)(gA + k0);
        uint4 a1 = *(const uint4*)(gA + k0 + 8);
        uint4 b0 = *(const uint4*)(gB + k0);
        uint4 b1 = *(const uint4*)(gB + k0 + 8);
        __syncthreads();
        *(uint4*)wA = a0; *(uint4*)(wA + 8) = a1;
        *(uint4*)wB = b0; *(uint4*)(wB + 8) = b1;
        __syncthreads();
        bf16x8 af[4], bf[4];
        #pragma unroll
        for (int mt = 0; mt < 4; mt++)
            af[mt] = *(const bf16x8*)(lA + (wr * 64 + mt * 16 + l15) * 40 + g4 * 8);
        #pragma unroll
        for (int nt = 0; nt < 4; nt++)
            bf[nt] = *(const bf16x8*)(lB + (wc * 64 + nt * 16 + l15) * 40 + g4 * 8);
        #pragma unroll
        for (int mt = 0; mt < 4; mt++)
            #pragma unroll
            for (int nt = 0; nt < 4; nt++)
                acc[mt][nt] = __builtin_amdgcn_mfma_f32_16x16x32_bf16(af[mt], bf[nt], acc[mt][nt], 0, 0, 0);
    }
    int orow = bm * 128 + wr * 64, ocol = bn * 128 + wc * 64;
    #pragma unroll
    for (int mt = 0; mt < 4; mt++)
        #pragma unroll
        for (int nt = 0; nt < 4; nt++)
            #pragma unroll
            for (int rg = 0; rg < 4; rg++)
                epi(orow + mt * 16 + g4 * 4 + rg, ocol + nt * 16 + l15, acc[mt][nt][rg]);
}

struct EpiQKV {
    const float* bias; u16* out;
    __device__ void operator()(int r, int c, float v) const {
        out[(size_t)r * 768 + c] = f2bf(v + bias[c]);
    }
};
struct EpiProj {
    const float* bias; const float* ls1; const u16* Abuf; u16* xa;
    __device__ void operator()(int r, int c, float v) const {
        float val = bf2f(Abuf[(size_t)r * 256 + c]) + (v + bias[c]) * ls1[c];
        xa[(size_t)r * 256 + c] = f2bf(val);
    }
};
struct EpiMLP1 {
    const float* bias; u16* h;
    __device__ void operator()(int r, int c, float v) const {
        float x = v + bias[c];
        float gl = 0.5f * x * (1.0f + erff(x * 0.70710678118654752f));
        h[(size_t)r * 1024 + c] = f2bf(gl);
    }
};
struct EpiMLP2 {
    const float* bias; const float* ls2; const u16* xa;
    const int* asy; const int* iwin; float* out;
    __device__ void operator()(int r, int c, float v) const {
        float val = bf2f(xa[(size_t)r * 256 + c]) + (v + bias[c]) * ls2[c];
        int flat = asy[r];
        int m = flat >> 6, p = flat & 63;
        int wdw = iwin[m];
        out[((size_t)wdw * P + p) * C + c] = val;
    }
};

// ---------- fused per-window attention ----------
// 1 block / window, 4 waves, 2 heads per wave. S = QK^T via 3x3 16x16x32 MFMA tiles
// (rows/keys padded 40->48 with zeros), wave-parallel masked softmax, PV via LDS-transposed V.
__global__ __launch_bounds__(256) void attn_kernel(const u16* __restrict__ QKV,
                                                   u16* __restrict__ out) {
    __shared__ u16 lds[4 * (48 * 80 + 32 * 80)];
    int m = blockIdx.x;
    int t = threadIdx.x, l = t & 63, w = t >> 6;
    int l15 = l & 15, g4 = l >> 4;
    u16* Pb = lds + w * (48 * 80 + 32 * 80);
    u16* Vt = Pb + 48 * 80;

    // zero own buffers once (cols >= used region must be finite zeros for MFMA)
    u32* z = (u32*)Pb;
    for (int i = l; i < (48 * 80 + 32 * 80) / 2; i += 64) z[i] = 0;

    const float scale = 0.17677669529663687f; // 32^-0.5

    for (int hh = 0; hh < 2; hh++) {
        int h = w + hh * 4;
        const u16* base = QKV + (size_t)m * REAL * 768 + h * 96;

        // stage V^T[d][key] into LDS (keys >=40 stay zero)
        for (int idx = l; idx < REAL * DH; idx += 64) {
            int kk = idx >> 5, d = idx & 31;
            Vt[d * 80 + kk] = base[(size_t)kk * 768 + 64 + d];
        }

        // S = Q K^T
        bf16x8 zf;
        #pragma unroll
        for (int i = 0; i < 8; i++) zf[i] = 0;
        bf16x8 qf[3], kf[3];
        #pragma unroll
        for (int mt = 0; mt < 3; mt++) {
            int q = mt * 16 + l15;
            qf[mt] = (q < REAL) ? *(const bf16x8*)(base + (size_t)q * 768 + g4 * 8) : zf;
        }
        #pragma unroll
        for (int nt = 0; nt < 3; nt++) {
            int kk = nt * 16 + l15;
            kf[nt] = (kk < REAL) ? *(const bf16x8*)(base + (size_t)kk * 768 + 32 + g4 * 8) : zf;
        }
        f32x4 s[3][3];
        #pragma unroll
        for (int a = 0; a < 3; a++)
            #pragma unroll
            for (int bb = 0; bb < 3; bb++)
                #pragma unroll
                for (int i = 0; i < 4; i++) s[a][bb][i] = 0.0f;
        #pragma unroll
        for (int mt = 0; mt < 3; mt++)
            #pragma unroll
            for (int nt = 0; nt < 3; nt++)
                s[mt][nt] = __builtin_amdgcn_mfma_f32_16x16x32_bf16(qf[mt], kf[nt], s[mt][nt], 0, 0, 0);

        // masked softmax per query row (row = g4*4+rg within tile; keys spread over l15 x 3 tiles)
        #pragma unroll
        for (int mt = 0; mt < 3; mt++) {
            #pragma unroll
            for (int rg = 0; rg < 4; rg++) {
                float v0 = s[mt][0][rg] * scale;
                float v1 = s[mt][1][rg] * scale;
                float v2 = s[mt][2][rg] * scale;
                bool k2ok = (32 + l15) < REAL;
                float mx = fmaxf(fmaxf(v0, v1), k2ok ? v2 : -1e30f);
                #pragma unroll
                for (int xm = 1; xm < 16; xm <<= 1) mx = fmaxf(mx, __shfl_xor(mx, xm));
                float e0 = __expf(v0 - mx);
                float e1 = __expf(v1 - mx);
                float e2 = k2ok ? __expf(v2 - mx) : 0.0f;
                float sm = e0 + e1 + e2;
                #pragma unroll
                for (int xm = 1; xm < 16; xm <<= 1) sm += __shfl_xor(sm, xm);
                float inv = 1.0f / sm;
                int q = mt * 16 + g4 * 4 + rg;
                Pb[q * 80 + l15]      = f2bf(e0 * inv);
                Pb[q * 80 + 16 + l15] = f2bf(e1 * inv);
                Pb[q * 80 + 32 + l15] = f2bf(e2 * inv);  // masked keys store exact 0
            }
        }

        // O = P V   (K padded to 64; cols 48..63 of Pb and keys 40..79 of Vt are zero)
        f32x4 o[3][2];
        #pragma unroll
        for (int a = 0; a < 3; a++)
            #pragma unroll
            for (int bb = 0; bb < 2; bb++)
                #pragma unroll
                for (int i = 0; i < 4; i++) o[a][bb][i] = 0.0f;
        #pragma unroll
        for (int kt = 0; kt < 2; kt++) {
            bf16x8 pf[3], vf[2];
            #pragma unroll
            for (int mt = 0; mt < 3; mt++)
                pf[mt] = *(const bf16x8*)(Pb + (mt * 16 + l15) * 80 + kt * 32 + g4 * 8);
            #pragma unroll
            for (int nt = 0; nt < 2; nt++)
                vf[nt] = *(const bf16x8*)(Vt + (nt * 16 + l15) * 80 + kt * 32 + g4 * 8);
            #pragma unroll
            for (int mt = 0; mt < 3; mt++)
                #pragma unroll
                for (int nt = 0; nt < 2; nt++)
                    o[mt][nt] = __builtin_amdgcn_mfma_f32_16x16x32_bf16(pf[mt], vf[nt], o[mt][nt], 0, 0, 0);
        }
        #pragma unroll
        for (int mt = 0; mt < 3; mt++)
            #pragma unroll
            for (int nt = 0; nt < 2; nt++)
                #pragma unroll
                for (int rg = 0; rg < 4; rg++) {
                    int q = mt * 16 + g4 * 4 + rg;
                    if (q < REAL)
                        out[((size_t)m * REAL + q) * C + h * DH + nt * 16 + l15] = f2bf(o[mt][nt][rg]);
                }
    }
}

extern "C" void kernel_launch(void* const* d_in, const int* in_sizes, int n_in,
                              void* d_out, int out_size, void* d_ws, size_t ws_size,
                              hipStream_t stream) {
    const float* x      = (const float*)d_in[0];
    const float* qkv_w  = (const float*)d_in[1];
    const float* qkv_b  = (const float*)d_in[2];
    const float* proj_w = (const float*)d_in[3];
    const float* proj_b = (const float*)d_in[4];
    const float* n1g    = (const float*)d_in[5];
    const float* n1b    = (const float*)d_in[6];
    const float* n2g    = (const float*)d_in[7];
    const float* n2b    = (const float*)d_in[8];
    const float* ls1    = (const float*)d_in[9];
    const float* ls2    = (const float*)d_in[10];
    const float* w1     = (const float*)d_in[11];
    const float* b1     = (const float*)d_in[12];
    const float* w2     = (const float*)d_in[13];
    const float* b2     = (const float*)d_in[14];
    const int*   iwin   = (const int*)d_in[15];
    const int*   asy    = (const int*)d_in[18];
    float* out = (float*)d_out;
    u16* ws = (u16*)d_ws;

    u16* WqkvT = ws + OFF_WQKVT;
    u16* ProjT = ws + OFF_PROJT;
    u16* W1T   = ws + OFF_W1T;
    u16* W2T   = ws + OFF_W2T;
    u16* Abuf  = ws + OFF_A;
    u16* QKV   = ws + OFF_QKV;
    u16* AttnO = ws + OFF_ATTNO;
    u16* XA    = ws + OFF_XA;
    u16* Hbuf  = ws + OFF_H;   // aliases QKV+AttnO (dead by then)

    prep_weights<<<3072, 256, 0, stream>>>(qkv_w, proj_w, w1, w2, ws);
    ln1_kernel<<<(NWIN * P) / 4, 256, 0, stream>>>(x, n1g, n1b, out);
    ln2_kernel<<<MROWS / 4, 256, 0, stream>>>(out, n2g, n2b, asy, iwin, Abuf);
    gemm_bt<768, 256, EpiQKV><<<(MROWS / 128) * 6, 256, 0, stream>>>(Abuf, WqkvT, EpiQKV{qkv_b, QKV});
    attn_kernel<<<MSEL, 256, 0, stream>>>(QKV, AttnO);
    gemm_bt<256, 256, EpiProj><<<(MROWS / 128) * 2, 256, 0, stream>>>(AttnO, ProjT, EpiProj{proj_b, ls1, Abuf, XA});
    gemm_bt<1024, 256, EpiMLP1><<<(MROWS / 128) * 8, 256, 0, stream>>>(XA, W1T, EpiMLP1{b1, Hbuf});
    gemm_bt<256, 1024, EpiMLP2><<<(MROWS / 128) * 2, 256, 0, stream>>>(Hbuf, W2T, EpiMLP2{b2, ls2, XA, asy, iwin, out});
}

// Round 2
// 517.687 us; speedup vs baseline: 1.1419x; 1.1419x over previous
//
#include <hip/hip_runtime.h>

typedef __attribute__((ext_vector_type(8))) short bf16x8;
typedef __attribute__((ext_vector_type(4))) float f32x4;
typedef unsigned short u16;
typedef unsigned int u32;

// ---------- constants ----------
#define NWIN 2048
#define P 64
#define C 256
#define MSEL 1536
#define KEEP 48
#define REAL 40
#define H 8
#define DH 32
#define MROWS (MSEL * REAL)          // 61440 rows in the compacted activation matrix

// ws layout (u16 element offsets)
#define OFF_WQKVT  0                  // [768][256]
#define OFF_PROJT  196608             // [256][256]
#define OFF_W1T    262144             // [1024][256]
#define OFF_W2T    524288             // [256][1024]
#define OFF_A      786432             // [61440][256] bf16  (LN2 rows)
#define OFF_QKV    16515072           // [61440][768] bf16
#define OFF_ATTNO  63700992           // [61440][256] bf16
#define OFF_XA     79429632           // [61440][256] bf16
#define OFF_H      16515072           // [61440][1024] bf16, aliases QKV+ATTNO (both dead)

__device__ __forceinline__ u16 f2bf(float f) {
    u32 u = __float_as_uint(f);
    u += 0x7FFF + ((u >> 16) & 1);   // RNE
    return (u16)(u >> 16);
}
__device__ __forceinline__ float bf2f(u16 h) { return __uint_as_float(((u32)h) << 16); }

// ---------- weight prep: fp32 [K][N] -> bf16 [N][K] ----------
__global__ __launch_bounds__(256) void prep_weights(const float* __restrict__ qkv_w,
                                                    const float* __restrict__ proj_w,
                                                    const float* __restrict__ w1,
                                                    const float* __restrict__ w2,
                                                    u16* __restrict__ ws) {
    int i = blockIdx.x * 256 + threadIdx.x;   // 786432 total
    float v; int o;
    if (i < 196608) {
        int n = i >> 8, k = i & 255; v = qkv_w[k * 768 + n]; o = OFF_WQKVT + i;
    } else if (i < 262144) {
        int j = i - 196608; int n = j >> 8, k = j & 255; v = proj_w[k * 256 + n]; o = i;
    } else if (i < 524288) {
        int j = i - 262144; int n = j >> 8, k = j & 255; v = w1[k * 1024 + n]; o = i;
    } else {
        int j = i - 524288; int n = j >> 10, k = j & 1023; v = w2[k * 256 + n]; o = i;
    }
    ws[o] = f2bf(v);
}

// ---------- LN1 over all (N*P, C) rows -> d_out fp32 ----------
__global__ __launch_bounds__(256) void ln1_kernel(const float* __restrict__ x,
                                                  const float* __restrict__ g,
                                                  const float* __restrict__ b,
                                                  float* __restrict__ out) {
    int row = blockIdx.x * 4 + (threadIdx.x >> 6);
    int l = threadIdx.x & 63;
    const float4 v = *(const float4*)(x + (size_t)row * C + l * 4);
    float s = v.x + v.y + v.z + v.w;
    float q = v.x * v.x + v.y * v.y + v.z * v.z + v.w * v.w;
    #pragma unroll
    for (int m = 1; m < 64; m <<= 1) { s += __shfl_xor(s, m); q += __shfl_xor(q, m); }
    float mu = s * (1.0f / C);
    float var = q * (1.0f / C) - mu * mu;
    float rs = rsqrtf(var + 1e-5f);
    float4 gg = *(const float4*)(g + l * 4);
    float4 bb = *(const float4*)(b + l * 4);
    float4 o;
    o.x = (v.x - mu) * rs * gg.x + bb.x;
    o.y = (v.y - mu) * rs * gg.y + bb.y;
    o.z = (v.z - mu) * rs * gg.z + bb.z;
    o.w = (v.w - mu) * rs * gg.w + bb.w;
    *(float4*)(out + (size_t)row * C + l * 4) = o;
}

// ---------- LN2 on real rows of selected windows -> A bf16 ----------
__global__ __launch_bounds__(256) void ln2_kernel(const float* __restrict__ ln1,
                                                  const float* __restrict__ g,
                                                  const float* __restrict__ b,
                                                  const int* __restrict__ asy,
                                                  const int* __restrict__ iwin,
                                                  u16* __restrict__ A) {
    int r = blockIdx.x * 4 + (threadIdx.x >> 6);
    int l = threadIdx.x & 63;
    int flat = asy[r];
    int m = flat >> 6, p = flat & 63;
    int w = iwin[m];
    const float4 v = *(const float4*)(ln1 + ((size_t)w * P + p) * C + l * 4);
    float s = v.x + v.y + v.z + v.w;
    float q = v.x * v.x + v.y * v.y + v.z * v.z + v.w * v.w;
    #pragma unroll
    for (int mm = 1; mm < 64; mm <<= 1) { s += __shfl_xor(s, mm); q += __shfl_xor(q, mm); }
    float mu = s * (1.0f / C);
    float var = q * (1.0f / C) - mu * mu;
    float rs = rsqrtf(var + 1e-5f);
    float4 gg = *(const float4*)(g + l * 4);
    float4 bb = *(const float4*)(b + l * 4);
    ushort4 o;
    o.x = f2bf((v.x - mu) * rs * gg.x + bb.x);
    o.y = f2bf((v.y - mu) * rs * gg.y + bb.y);
    o.z = f2bf((v.z - mu) * rs * gg.z + bb.z);
    o.w = f2bf((v.w - mu) * rs * gg.w + bb.w);
    *(ushort4*)(A + (size_t)r * C + l * 4) = o;
}

// ---------- 128x128-tile bf16 MFMA GEMM, m97 structure ----------
// C = A[MxK] * B^T[NxK]. BK=64, linear LDS [128][64] filled by global_load_lds w=16,
// source pre-swizzled (colgrp = s ^ (row&7)), ds_read_b128 applies the same XOR.
template <int N, int K, class Epi>
__global__ __launch_bounds__(256) void gemm_bt(const u16* __restrict__ A,
                                               const u16* __restrict__ B, Epi epi,
                                               int chunk) {
    constexpr int NB = N / 128;
    int bid = blockIdx.x;
    bid = (bid & 7) * chunk + (bid >> 3);          // XCD-aware swizzle (grid % 8 == 0)
    int bm = bid / NB, bn = bid % NB;
    __shared__ u16 lA[128 * 64], lB[128 * 64];
    int t = threadIdx.x;
    int l = t & 63, w = t >> 6;
    int wr = w >> 1, wc = w & 1;
    int l15 = l & 15, g4 = l >> 4;
    int xr = l15 & 7;                               // read-side XOR (row&7 == l15&7)

    f32x4 acc[4][4];
    #pragma unroll
    for (int a = 0; a < 4; a++)
        #pragma unroll
        for (int bb = 0; bb < 4; bb++)
            #pragma unroll
            for (int i = 0; i < 4; i++) acc[a][bb][i] = 0.0f;

    // staging geometry: wave w fills LDS bytes [w*4KB, (w+1)*4KB), 4 issues of 1KB.
    // linear lds elem off = w*2048 + j*512 + l*8 -> row = w*32 + j*8 + (l>>3), slot = l&7.
    int rbase = w * 32 + (l >> 3);
    int cg = (l & 7) ^ (l >> 3);                    // pre-swizzled source col-group
    const u16* gA = A + (size_t)(bm * 128 + rbase) * K + cg * 8;
    const u16* gB = B + (size_t)(bn * 128 + rbase) * K + cg * 8;

    for (int k0 = 0; k0 < K; k0 += 64) {
        __syncthreads();                            // prev compute done before overwrite
        #pragma unroll
        for (int j = 0; j < 4; j++)
            __builtin_amdgcn_global_load_lds(
                (const __attribute__((address_space(1))) u32*)(gA + (size_t)j * 8 * K + k0),
                (__attribute__((address_space(3))) u32*)(lA + w * 2048 + j * 512), 16, 0, 0);
        #pragma unroll
        for (int j = 0; j < 4; j++)
            __builtin_amdgcn_global_load_lds(
                (const __attribute__((address_space(1))) u32*)(gB + (size_t)j * 8 * K + k0),
                (__attribute__((address_space(3))) u32*)(lB + w * 2048 + j * 512), 16, 0, 0);
        __syncthreads();                            // vmcnt(0) drained by compiler here
        #pragma unroll
        for (int kk = 0; kk < 2; kk++) {
            bf16x8 af[4], bfr[4];
            #pragma unroll
            for (int mt = 0; mt < 4; mt++)
                af[mt] = *(const bf16x8*)(lA + (wr * 64 + mt * 16 + l15) * 64
                                             + ((kk * 4 + g4) ^ xr) * 8);
            #pragma unroll
            for (int nt = 0; nt < 4; nt++)
                bfr[nt] = *(const bf16x8*)(lB + (wc * 64 + nt * 16 + l15) * 64
                                              + ((kk * 4 + g4) ^ xr) * 8);
            #pragma unroll
            for (int mt = 0; mt < 4; mt++)
                #pragma unroll
                for (int nt = 0; nt < 4; nt++)
                    acc[mt][nt] = __builtin_amdgcn_mfma_f32_16x16x32_bf16(af[mt], bfr[nt], acc[mt][nt], 0, 0, 0);
        }
    }
    int orow = bm * 128 + wr * 64, ocol = bn * 128 + wc * 64;
    #pragma unroll
    for (int mt = 0; mt < 4; mt++)
        #pragma unroll
        for (int nt = 0; nt < 4; nt++)
            #pragma unroll
            for (int rg = 0; rg < 4; rg++)
                epi(orow + mt * 16 + g4 * 4 + rg, ocol + nt * 16 + l15, acc[mt][nt][rg]);
}

struct EpiQKV {
    const float* bias; u16* out;
    __device__ void operator()(int r, int c, float v) const {
        out[(size_t)r * 768 + c] = f2bf(v + bias[c]);
    }
};
struct EpiProj {
    const float* bias; const float* ls1; const u16* Abuf; u16* xa;
    __device__ void operator()(int r, int c, float v) const {
        float val = bf2f(Abuf[(size_t)r * 256 + c]) + (v + bias[c]) * ls1[c];
        xa[(size_t)r * 256 + c] = f2bf(val);
    }
};
struct EpiMLP1 {
    const float* bias; u16* h;
    __device__ void operator()(int r, int c, float v) const {
        float x = v + bias[c];
        float gl = 0.5f * x * (1.0f + erff(x * 0.70710678118654752f));
        h[(size_t)r * 1024 + c] = f2bf(gl);
    }
};
struct EpiMLP2 {
    const float* bias; const float* ls2; const u16* xa;
    const int* asy; const int* iwin; float* out;
    __device__ void operator()(int r, int c, float v) const {
        float val = bf2f(xa[(size_t)r * 256 + c]) + (v + bias[c]) * ls2[c];
        int flat = asy[r];
        int m = flat >> 6, p = flat & 63;
        int wdw = iwin[m];
        out[((size_t)wdw * P + p) * C + c] = val;
    }
};

// ---------- fused per-window attention ----------
__global__ __launch_bounds__(256) void attn_kernel(const u16* __restrict__ QKV,
                                                   u16* __restrict__ out) {
    __shared__ u16 lds[4 * (48 * 80 + 32 * 80)];
    int m = blockIdx.x;
    int t = threadIdx.x, l = t & 63, w = t >> 6;
    int l15 = l & 15, g4 = l >> 4;
    u16* Pb = lds + w * (48 * 80 + 32 * 80);
    u16* Vt = Pb + 48 * 80;

    u32* z = (u32*)Pb;
    for (int i = l; i < (48 * 80 + 32 * 80) / 2; i += 64) z[i] = 0;

    const float scale = 0.17677669529663687f; // 32^-0.5

    for (int hh = 0; hh < 2; hh++) {
        int h = w + hh * 4;
        const u16* base = QKV + (size_t)m * REAL * 768 + h * 96;

        // stage V^T[d][key] into LDS: 16B vector global loads + LDS scatter
        for (int i = l; i < REAL * 4; i += 64) {
            int kk = i >> 2, dg = i & 3;
            bf16x8 vv = *(const bf16x8*)(base + (size_t)kk * 768 + 64 + dg * 8);
            #pragma unroll
            for (int j = 0; j < 8; j++) Vt[(dg * 8 + j) * 80 + kk] = vv[j];
        }

        // S = Q K^T
        bf16x8 zf;
        #pragma unroll
        for (int i = 0; i < 8; i++) zf[i] = 0;
        bf16x8 qf[3], kf[3];
        #pragma unroll
        for (int mt = 0; mt < 3; mt++) {
            int q = mt * 16 + l15;
            qf[mt] = (q < REAL) ? *(const bf16x8*)(base + (size_t)q * 768 + g4 * 8) : zf;
        }
        #pragma unroll
        for (int nt = 0; nt < 3; nt++) {
            int kk = nt * 16 + l15;
            kf[nt] = (kk < REAL) ? *(const bf16x8*)(base + (size_t)kk * 768 + 32 + g4 * 8) : zf;
        }
        f32x4 s[3][3];
        #pragma unroll
        for (int a = 0; a < 3; a++)
            #pragma unroll
            for (int bb = 0; bb < 3; bb++)
                #pragma unroll
                for (int i = 0; i < 4; i++) s[a][bb][i] = 0.0f;
        #pragma unroll
        for (int mt = 0; mt < 3; mt++)
            #pragma unroll
            for (int nt = 0; nt < 3; nt++)
                s[mt][nt] = __builtin_amdgcn_mfma_f32_16x16x32_bf16(qf[mt], kf[nt], s[mt][nt], 0, 0, 0);

        // masked softmax per query row
        #pragma unroll
        for (int mt = 0; mt < 3; mt++) {
            #pragma unroll
            for (int rg = 0; rg < 4; rg++) {
                float v0 = s[mt][0][rg] * scale;
                float v1 = s[mt][1][rg] * scale;
                float v2 = s[mt][2][rg] * scale;
                bool k2ok = (32 + l15) < REAL;
                float mx = fmaxf(fmaxf(v0, v1), k2ok ? v2 : -1e30f);
                #pragma unroll
                for (int xm = 1; xm < 16; xm <<= 1) mx = fmaxf(mx, __shfl_xor(mx, xm));
                float e0 = __expf(v0 - mx);
                float e1 = __expf(v1 - mx);
                float e2 = k2ok ? __expf(v2 - mx) : 0.0f;
                float sm = e0 + e1 + e2;
                #pragma unroll
                for (int xm = 1; xm < 16; xm <<= 1) sm += __shfl_xor(sm, xm);
                float inv = 1.0f / sm;
                int q = mt * 16 + g4 * 4 + rg;
                Pb[q * 80 + l15]      = f2bf(e0 * inv);
                Pb[q * 80 + 16 + l15] = f2bf(e1 * inv);
                Pb[q * 80 + 32 + l15] = f2bf(e2 * inv);
            }
        }

        // O = P V
        f32x4 o[3][2];
        #pragma unroll
        for (int a = 0; a < 3; a++)
            #pragma unroll
            for (int bb = 0; bb < 2; bb++)
                #pragma unroll
                for (int i = 0; i < 4; i++) o[a][bb][i] = 0.0f;
        #pragma unroll
        for (int kt = 0; kt < 2; kt++) {
            bf16x8 pf[3], vf[2];
            #pragma unroll
            for (int mt = 0; mt < 3; mt++)
                pf[mt] = *(const bf16x8*)(Pb + (mt * 16 + l15) * 80 + kt * 32 + g4 * 8);
            #pragma unroll
            for (int nt = 0; nt < 2; nt++)
                vf[nt] = *(const bf16x8*)(Vt + (nt * 16 + l15) * 80 + kt * 32 + g4 * 8);
            #pragma unroll
            for (int mt = 0; mt < 3; mt++)
                #pragma unroll
                for (int nt = 0; nt < 2; nt++)
                    o[mt][nt] = __builtin_amdgcn_mfma_f32_16x16x32_bf16(pf[mt], vf[nt], o[mt][nt], 0, 0, 0);
        }
        #pragma unroll
        for (int mt = 0; mt < 3; mt++)
            #pragma unroll
            for (int nt = 0; nt < 2; nt++)
                #pragma unroll
                for (int rg = 0; rg < 4; rg++) {
                    int q = mt * 16 + g4 * 4 + rg;
                    if (q < REAL)
                        out[((size_t)m * REAL + q) * C + h * DH + nt * 16 + l15] = f2bf(o[mt][nt][rg]);
                }
    }
}

extern "C" void kernel_launch(void* const* d_in, const int* in_sizes, int n_in,
                              void* d_out, int out_size, void* d_ws, size_t ws_size,
                              hipStream_t stream) {
    const float* x      = (const float*)d_in[0];
    const float* qkv_w  = (const float*)d_in[1];
    const float* qkv_b  = (const float*)d_in[2];
    const float* proj_w = (const float*)d_in[3];
    const float* proj_b = (const float*)d_in[4];
    const float* n1g    = (const float*)d_in[5];
    const float* n1b    = (const float*)d_in[6];
    const float* n2g    = (const float*)d_in[7];
    const float* n2b    = (const float*)d_in[8];
    const float* ls1    = (const float*)d_in[9];
    const float* ls2    = (const float*)d_in[10];
    const float* w1     = (const float*)d_in[11];
    const float* b1     = (const float*)d_in[12];
    const float* w2     = (const float*)d_in[13];
    const float* b2     = (const float*)d_in[14];
    const int*   iwin   = (const int*)d_in[15];
    const int*   asy    = (const int*)d_in[18];
    float* out = (float*)d_out;
    u16* ws = (u16*)d_ws;

    u16* WqkvT = ws + OFF_WQKVT;
    u16* ProjT = ws + OFF_PROJT;
    u16* W1T   = ws + OFF_W1T;
    u16* W2T   = ws + OFF_W2T;
    u16* Abuf  = ws + OFF_A;
    u16* QKV   = ws + OFF_QKV;
    u16* AttnO = ws + OFF_ATTNO;
    u16* XA    = ws + OFF_XA;
    u16* Hbuf  = ws + OFF_H;   // aliases QKV+AttnO (dead by then)

    prep_weights<<<3072, 256, 0, stream>>>(qkv_w, proj_w, w1, w2, ws);
    ln1_kernel<<<(NWIN * P) / 4, 256, 0, stream>>>(x, n1g, n1b, out);
    ln2_kernel<<<MROWS / 4, 256, 0, stream>>>(out, n2g, n2b, asy, iwin, Abuf);
    {
        int nwg = (MROWS / 128) * 6;
        gemm_bt<768, 256, EpiQKV><<<nwg, 256, 0, stream>>>(Abuf, WqkvT, EpiQKV{qkv_b, QKV}, nwg / 8);
    }
    attn_kernel<<<MSEL, 256, 0, stream>>>(QKV, AttnO);
    {
        int nwg = (MROWS / 128) * 2;
        gemm_bt<256, 256, EpiProj><<<nwg, 256, 0, stream>>>(AttnO, ProjT, EpiProj{proj_b, ls1, Abuf, XA}, nwg / 8);
    }
    {
        int nwg = (MROWS / 128) * 8;
        gemm_bt<1024, 256, EpiMLP1><<<nwg, 256, 0, stream>>>(XA, W1T, EpiMLP1{b1, Hbuf}, nwg / 8);
    }
    {
        int nwg = (MROWS / 128) * 2;
        gemm_bt<256, 1024, EpiMLP2><<<nwg, 256, 0, stream>>>(Hbuf, W2T, EpiMLP2{b2, ls2, XA, asy, iwin, out}, nwg / 8);
    }
}